// Round 1
// baseline (482.759 us; speedup 1.0000x reference)
//
#include <hip/hip_runtime.h>

#define E_TOTAL 600000
#define LDH 264  // LDS row stride (elements); 264*2B = 528B -> bank spread, 16B aligned

typedef __attribute__((ext_vector_type(8))) short short8;
typedef __attribute__((ext_vector_type(4))) float f32x4;

__device__ __forceinline__ unsigned short f2bf(float f) {
  union { float f; unsigned u; } v; v.f = f;
  unsigned r = v.u + 0x7fffu + ((v.u >> 16) & 1u);  // RNE
  return (unsigned short)(r >> 16);
}

// W1 [k=256][n=256] f32 -> W1t [n=256][k=256] bf16 ; W2 [k=256][n=64] -> W2t [n=64][k=256]
__global__ __launch_bounds__(256) void prep_weights(
    const float* __restrict__ W1, const float* __restrict__ W2,
    unsigned short* __restrict__ W1t, unsigned short* __restrict__ W2t) {
  int tid = blockIdx.x * 256 + threadIdx.x;  // 0..65535
  {
    int n = tid >> 8, k = tid & 255;
    W1t[tid] = f2bf(W1[k * 256 + n]);
  }
  if (tid < 64 * 256) {
    int n = tid >> 8, k = tid & 255;
    W2t[tid] = f2bf(W2[k * 64 + n]);
  }
}

__global__ __launch_bounds__(256) void edge_mlp(
    const float* __restrict__ x, const int* __restrict__ ei,
    const unsigned short* __restrict__ W1t, const unsigned short* __restrict__ W2t,
    const float* __restrict__ b1, const float* __restrict__ b2,
    float* __restrict__ out) {
  __shared__ unsigned short lds[64 * LDH];  // 33792 B: feat tile, then reused for hidden

  const int tid = threadIdx.x;
  const int base = blockIdx.x * 64;
  const int* __restrict__ srcI = ei;             // edge_index[0]
  const int* __restrict__ dstI = ei + E_TOTAL;   // edge_index[1]

  // ---- gather feat[64][256] bf16 into LDS (coalesced: 8 floats per thread-chunk) ----
#pragma unroll
  for (int i = 0; i < 8; ++i) {
    int c = tid + 256 * i;      // 0..2047
    int e = c >> 5;             // 0..63
    int kb = (c & 31) * 8;      // 0..248
    int node = (kb < 128) ? srcI[base + e] : dstI[base + e];
    int off = (kb < 128) ? kb : (kb - 128);
    const float* p = x + node * 128 + off;
    f32x4 v0 = *(const f32x4*)p;
    f32x4 v1 = *(const f32x4*)(p + 4);
    short8 pk;
    pk[0] = (short)f2bf(v0[0]); pk[1] = (short)f2bf(v0[1]);
    pk[2] = (short)f2bf(v0[2]); pk[3] = (short)f2bf(v0[3]);
    pk[4] = (short)f2bf(v1[0]); pk[5] = (short)f2bf(v1[1]);
    pk[6] = (short)f2bf(v1[2]); pk[7] = (short)f2bf(v1[3]);
    *(short8*)&lds[e * LDH + kb] = pk;
  }
  __syncthreads();

  const int lane = tid & 63;
  const int w = tid >> 6;      // wave 0..3
  const int m = lane & 15;     // row-in-tile (A) / col (B,C)
  const int q = lane >> 4;     // quad

  // ---- phase 1: hidden[64][256] = relu(feat @ W1 + b1) ----
  // wave w: N-tiles w*4..w*4+3 (global cols), all 4 M-tiles -> B-frag reuse x4
  f32x4 acc[4][4];
#pragma unroll
  for (int mt = 0; mt < 4; ++mt)
#pragma unroll
    for (int nt = 0; nt < 4; ++nt)
      acc[mt][nt] = (f32x4){0.f, 0.f, 0.f, 0.f};

#pragma unroll
  for (int kk = 0; kk < 8; ++kk) {
    const int ko = kk * 32 + q * 8;
    short8 a[4], b[4];
#pragma unroll
    for (int mt = 0; mt < 4; ++mt)
      a[mt] = *(const short8*)&lds[(mt * 16 + m) * LDH + ko];
#pragma unroll
    for (int nt = 0; nt < 4; ++nt)
      b[nt] = *(const short8*)&W1t[((w * 4 + nt) * 16 + m) * 256 + ko];
#pragma unroll
    for (int nt = 0; nt < 4; ++nt)
#pragma unroll
      for (int mt = 0; mt < 4; ++mt)
        acc[mt][nt] = __builtin_amdgcn_mfma_f32_16x16x32_bf16(a[mt], b[nt], acc[mt][nt], 0, 0, 0);
  }

  float bias1[4];
#pragma unroll
  for (int nt = 0; nt < 4; ++nt) bias1[nt] = b1[(w * 4 + nt) * 16 + m];

  __syncthreads();  // all feat reads complete before overwrite
#pragma unroll
  for (int mt = 0; mt < 4; ++mt)
#pragma unroll
    for (int nt = 0; nt < 4; ++nt)
#pragma unroll
      for (int r = 0; r < 4; ++r) {
        float h = acc[mt][nt][r] + bias1[nt];
        h = h > 0.f ? h : 0.f;
        // C layout: row = mt*16 + q*4 + r, col = (w*4+nt)*16 + m
        lds[(mt * 16 + q * 4 + r) * LDH + (w * 4 + nt) * 16 + m] = f2bf(h);
      }
  __syncthreads();

  // ---- phase 2: out[64][64] = hidden @ W2 + b2 ; wave w owns M-tile w ----
  f32x4 acc2[4];
#pragma unroll
  for (int nt = 0; nt < 4; ++nt) acc2[nt] = (f32x4){0.f, 0.f, 0.f, 0.f};

#pragma unroll
  for (int kk = 0; kk < 8; ++kk) {
    const int ko = kk * 32 + q * 8;
    short8 a = *(const short8*)&lds[(w * 16 + m) * LDH + ko];
#pragma unroll
    for (int nt = 0; nt < 4; ++nt) {
      short8 b = *(const short8*)&W2t[(nt * 16 + m) * 256 + ko];
      acc2[nt] = __builtin_amdgcn_mfma_f32_16x16x32_bf16(a, b, acc2[nt], 0, 0, 0);
    }
  }

#pragma unroll
  for (int nt = 0; nt < 4; ++nt) {
    float bb = b2[nt * 16 + m];
#pragma unroll
    for (int r = 0; r < 4; ++r) {
      int e = base + w * 16 + q * 4 + r;
      out[(long)e * 64 + nt * 16 + m] = acc2[nt][r] + bb;
    }
  }
}

extern "C" void kernel_launch(void* const* d_in, const int* in_sizes, int n_in,
                              void* d_out, int out_size, void* d_ws, size_t ws_size,
                              hipStream_t stream) {
  const float* x  = (const float*)d_in[0];
  const int*   ei = (const int*)d_in[1];
  const float* W1 = (const float*)d_in[2];
  const float* b1 = (const float*)d_in[3];
  const float* W2 = (const float*)d_in[4];
  const float* b2 = (const float*)d_in[5];
  float* out = (float*)d_out;

  unsigned short* W1t = (unsigned short*)d_ws;       // 65536 bf16 = 128 KB
  unsigned short* W2t = W1t + 256 * 256;             // 16384 bf16 = 32 KB

  prep_weights<<<256, 256, 0, stream>>>(W1, W2, W1t, W2t);
  edge_mlp<<<E_TOTAL / 64, 256, 0, stream>>>(x, ei, W1t, W2t, b1, b2, out);
}

// Round 2
// 372.313 us; speedup vs baseline: 1.2966x; 1.2966x over previous
//
#include <hip/hip_runtime.h>

#define E_TOTAL 600000
#define NTILES (E_TOTAL / 64)
#define LDH 264  // LDS row stride in shorts; 528 B -> balanced banks, 16B aligned

typedef __attribute__((ext_vector_type(8))) short short8;
typedef __attribute__((ext_vector_type(4))) float f32x4;

__device__ __forceinline__ unsigned f2bf_u(float f) {
  union { float f; unsigned u; } v; v.f = f;
  return (v.u + 0x7fffu + ((v.u >> 16) & 1u)) >> 16;  // RNE
}

// LDS-only barrier: drain ds ops, do NOT drain vmcnt (global loads stay in flight).
__device__ __forceinline__ void ldsBarrier() {
  asm volatile("s_waitcnt lgkmcnt(0)\n\ts_barrier" ::: "memory");
}

// ---- weight prep: tiled transpose+cast. W1[k][n]->W1t[n][k] bf16, W2 likewise ----
__global__ __launch_bounds__(256) void prep_weights(
    const float* __restrict__ W1, const float* __restrict__ W2,
    unsigned short* __restrict__ W1t, unsigned short* __restrict__ W2t) {
  __shared__ float t[32][33];
  int bid = blockIdx.x;
  const float* S; unsigned short* D; int k0, n0, N;
  if (bid < 64) { S = W1; D = W1t; N = 256; k0 = (bid >> 3) * 32; n0 = (bid & 7) * 32; }
  else { bid -= 64; S = W2; D = W2t; N = 64; k0 = (bid >> 1) * 32; n0 = (bid & 1) * 32; }
  int tx = threadIdx.x & 31, ty = threadIdx.x >> 5;
#pragma unroll
  for (int i = 0; i < 32; i += 8) t[ty + i][tx] = S[(k0 + ty + i) * N + n0 + tx];
  __syncthreads();
#pragma unroll
  for (int i = 0; i < 32; i += 8)
    D[(n0 + ty + i) * 256 + k0 + tx] = (unsigned short)f2bf_u(t[tx][ty + i]);
}

// ---- fused edge MLP: one 64-edge tile per block ----
__global__ __launch_bounds__(256, 3) void edge_mlp(
    const float* __restrict__ x, const int* __restrict__ ei,
    const unsigned short* __restrict__ W1t, const unsigned short* __restrict__ W2t,
    const float* __restrict__ b1, const float* __restrict__ b2,
    float* __restrict__ out) {
  __shared__ __align__(16) unsigned short lds[64 * LDH];  // feat tile, reused as hidden
  __shared__ float ldsb1[256];
  __shared__ float ldsb2[64];

  const int tid = threadIdx.x;
  const int base = blockIdx.x * 64;
  const int* __restrict__ srcI = ei;
  const int* __restrict__ dstI = ei + E_TOTAL;

  const int lane = tid & 63;
  const int w = tid >> 6;    // wave 0..3
  const int m = lane & 15;
  const int q = lane >> 4;

  // ---- issue order matters (vmcnt is in-order): b2, b1, idx, gather ----
  float b2tmp = 0.f;
  if (tid < 64) b2tmp = b2[tid];
  float b1tmp = b1[tid];

  const int kb = (tid & 31) * 8;        // 0..248, fixed per thread
  const int xo = kb & 127;
  const int e0 = tid >> 5;              // 0..7
  const int* __restrict__ idxp = (kb < 128) ? srcI : dstI;

  int nodes[8];
#pragma unroll
  for (int i = 0; i < 8; ++i) nodes[i] = idxp[base + e0 + 8 * i];

  f32x4 g0[8], g1[8];
#pragma unroll
  for (int i = 0; i < 8; ++i) {
    const float* p = x + (long)nodes[i] * 128 + xo;
    g0[i] = *(const f32x4*)p;
    g1[i] = *(const f32x4*)(p + 4);
  }

  // stage biases into LDS (waits only b1/b2 - oldest in queue)
  ldsb1[tid] = b1tmp;
  if (tid < 64) ldsb2[tid] = b2tmp;

  // convert + store feat tile (waits gather)
#pragma unroll
  for (int i = 0; i < 8; ++i) {
    short8 s;
#pragma unroll
    for (int j = 0; j < 4; ++j) {
      s[j]     = (short)f2bf_u(g0[i][j]);
      s[4 + j] = (short)f2bf_u(g1[i][j]);
    }
    *(short8*)&lds[(e0 + 8 * i) * LDH + kb] = s;
  }

  // W1t A-frag base offsets (elements); wave w owns n1 range [w*64, w*64+64)
  int w1off[4];
#pragma unroll
  for (int nt = 0; nt < 4; ++nt) w1off[nt] = ((w * 4 + nt) * 16 + m) * 256 + q * 8;
  const int w2off = (w * 16 + m) * 256 + q * 8;

  // issue kk=0 W1 frags BEFORE barrier so latency hides behind it
  short8 wa[2][4];
#pragma unroll
  for (int nt = 0; nt < 4; ++nt) wa[0][nt] = *(const short8*)&W1t[w1off[nt]];

  ldsBarrier();  // feat visible

  // ---- phase 1: D[n1][e] = sum_k W1t[n1][k] * feat[e][k] ----
  f32x4 acc[4][4];
#pragma unroll
  for (int nt = 0; nt < 4; ++nt)
#pragma unroll
    for (int mt = 0; mt < 4; ++mt) acc[nt][mt] = (f32x4){0.f, 0.f, 0.f, 0.f};

  short8 w2f[8];
#pragma unroll
  for (int kk = 0; kk < 8; ++kk) {
    const int cur = kk & 1, nxt = cur ^ 1;
    if (kk < 7) {
#pragma unroll
      for (int nt = 0; nt < 4; ++nt)
        wa[nxt][nt] = *(const short8*)&W1t[w1off[nt] + (kk + 1) * 32];
    }
    if (kk == 6) {  // prefetch W2 frags; consumed in phase 2 (no newer loads follow)
#pragma unroll
      for (int j = 0; j < 8; ++j) w2f[j] = *(const short8*)&W2t[w2off + j * 32];
    }
    short8 f[4];
#pragma unroll
    for (int mt = 0; mt < 4; ++mt)
      f[mt] = *(const short8*)&lds[(mt * 16 + m) * LDH + kk * 32 + q * 8];
#pragma unroll
    for (int nt = 0; nt < 4; ++nt)
#pragma unroll
      for (int mt = 0; mt < 4; ++mt)
        acc[nt][mt] = __builtin_amdgcn_mfma_f32_16x16x32_bf16(wa[cur][nt], f[mt], acc[nt][mt], 0, 0, 0);
  }

  ldsBarrier();  // feat reads done; safe to overwrite with hidden

  // ---- bias + relu + packed hidden write: hidden[e][n1], 4 consecutive n1 per lane ----
  f32x4 bias[4];
#pragma unroll
  for (int nt = 0; nt < 4; ++nt) bias[nt] = *(const f32x4*)&ldsb1[w * 64 + nt * 16 + q * 4];
#pragma unroll
  for (int nt = 0; nt < 4; ++nt)
#pragma unroll
    for (int mt = 0; mt < 4; ++mt) {
      float h0 = fmaxf(acc[nt][mt][0] + bias[nt][0], 0.f);
      float h1 = fmaxf(acc[nt][mt][1] + bias[nt][1], 0.f);
      float h2 = fmaxf(acc[nt][mt][2] + bias[nt][2], 0.f);
      float h3 = fmaxf(acc[nt][mt][3] + bias[nt][3], 0.f);
      uint2 pk;
      pk.x = f2bf_u(h0) | (f2bf_u(h1) << 16);
      pk.y = f2bf_u(h2) | (f2bf_u(h3) << 16);
      *(uint2*)&lds[(mt * 16 + m) * LDH + w * 64 + nt * 16 + q * 4] = pk;
    }

  ldsBarrier();  // hidden visible

  // ---- phase 2: D[n2][e] = sum_k W2t[n2][k] * hidden[e][k] (VMEM-free) ----
  f32x4 acc2[4];
#pragma unroll
  for (int mt = 0; mt < 4; ++mt) acc2[mt] = (f32x4){0.f, 0.f, 0.f, 0.f};
#pragma unroll
  for (int kk = 0; kk < 8; ++kk) {
#pragma unroll
    for (int mt = 0; mt < 4; ++mt) {
      short8 h = *(const short8*)&lds[(mt * 16 + m) * LDH + kk * 32 + q * 8];
      acc2[mt] = __builtin_amdgcn_mfma_f32_16x16x32_bf16(w2f[kk], h, acc2[mt], 0, 0, 0);
    }
  }

  f32x4 b2v = *(const f32x4*)&ldsb2[w * 16 + q * 4];
#pragma unroll
  for (int mt = 0; mt < 4; ++mt) {
    f32x4 o;
#pragma unroll
    for (int r = 0; r < 4; ++r) o[r] = acc2[mt][r] + b2v[r];
    *(f32x4*)&out[(base + mt * 16 + m) * 64 + w * 16 + q * 4] = o;
  }
}

extern "C" void kernel_launch(void* const* d_in, const int* in_sizes, int n_in,
                              void* d_out, int out_size, void* d_ws, size_t ws_size,
                              hipStream_t stream) {
  const float* x  = (const float*)d_in[0];
  const int*   ei = (const int*)d_in[1];
  const float* W1 = (const float*)d_in[2];
  const float* b1 = (const float*)d_in[3];
  const float* W2 = (const float*)d_in[4];
  const float* b2 = (const float*)d_in[5];
  float* out = (float*)d_out;

  unsigned short* W1t = (unsigned short*)d_ws;   // 256*256 bf16
  unsigned short* W2t = W1t + 256 * 256;         // 64*256 bf16

  prep_weights<<<80, 256, 0, stream>>>(W1, W2, W1t, W2t);
  edge_mlp<<<NTILES, 256, 0, stream>>>(x, ei, W1t, W2t, b1, b2, out);
}